// Round 9
// baseline (8881.721 us; speedup 1.0000x reference)
//
#include <hip/hip_runtime.h>

// ---------------------------------------------------------------------------
// Scaled HMM forward, B=32 rows, T=10000 serial steps, N=132 states.
// ROUND-9: round-8 math (verified absmax 0.0), loop ROLLED to 1 step/iter.
// Hypothesis: rounds 7/8 were instruction-FETCH bound -- the 8x-unrolled
// body was ~1600 instrs (~13 KB) per chunk; a single wave must fetch all of
// it every pass, and fetch stalls show in NO pipe counter (MfmaUtil 18%/CU +
// VALUBusy 12%/CU + ds ~= 600 cy accounted of 1810 measured).
// Rolled body ~210 instrs (~1.7 KB). Obs: transposed layout obT[t][32] +
// 3-deep register prefetch pipeline (one u16 L2 load per step).
// Recurrence (unchanged): D'[j][b] = sum_i At[j][i]*Y[i][b] via
// v_mfma_f32_16x16x16f16; D rows == B k-slots per lane, so step t's output
// fragment converts in-lane (pkrtz) to step t+1's B operand. z-normalization
// with 1-lag scale g=128*rcp(z_prev), exact log bookkeeping.
// ---------------------------------------------------------------------------

typedef _Float16 half_t;
typedef half_t h2 __attribute__((ext_vector_type(2)));
typedef half_t half4 __attribute__((ext_vector_type(4)));
typedef float  f32x4 __attribute__((ext_vector_type(4)));
typedef unsigned int uint2v __attribute__((ext_vector_type(2)));

#define FDOT2(a, b, acc) __builtin_amdgcn_fdot2((a), (b), (acc), false)

#define NS 132
#define NSP 144        // padded states: 9 tiles of 16
#define NA 126
#define EMS 148        // em row stride in halves (296 B, bank-spread)
#define TLEN 10000
#define TPAD 10004     // obs rows incl. prefetch-overrun pad
#define NBATCH 32

// workspace layout (bytes)
#define OBS_OFF 0                    // TPAD*32*2       = 640256
#define AT_OFF  640256               // 81*64*8 (uint2) = 41472
#define EM_OFF  (AT_OFF + 41472)     // 126*148*2       = 37296
#define I0_OFF  (EM_OFF + NA*EMS*2)  // 144*4           = 576

static __device__ __forceinline__ h2 bch2(unsigned int u) {
    return __builtin_bit_cast(h2, u);
}
static __device__ __forceinline__ unsigned int bcu(h2 v) {
    return __builtin_bit_cast(unsigned int, v);
}
static __device__ __forceinline__ h2 pkrtz(float a, float b) {
    return __builtin_bit_cast(h2, __builtin_amdgcn_cvt_pkrtz(a, b));
}
static __device__ __forceinline__ half4 mk4(h2 a, h2 b) {
    uint2 u = make_uint2(bcu(a), bcu(b));
    return __builtin_bit_cast(half4, u);
}

// lane-crossing adds on the VALU (gfx950 permlane*_swap), DS-pipe fallback
static __device__ __forceinline__ float xadd16(float v) {
#if __has_builtin(__builtin_amdgcn_permlane16_swap)
    uint2v r = __builtin_amdgcn_permlane16_swap(
        __builtin_bit_cast(unsigned int, v), __builtin_bit_cast(unsigned int, v),
        false, false);
    return __builtin_bit_cast(float, r[0]) + __builtin_bit_cast(float, r[1]);
#else
    return v + __shfl_xor(v, 16, 64);
#endif
}
static __device__ __forceinline__ float xadd32(float v) {
#if __has_builtin(__builtin_amdgcn_permlane32_swap)
    uint2v r = __builtin_amdgcn_permlane32_swap(
        __builtin_bit_cast(unsigned int, v), __builtin_bit_cast(unsigned int, v),
        false, false);
    return __builtin_bit_cast(float, r[0]) + __builtin_bit_cast(float, r[1]);
#else
    return v + __shfl_xor(v, 32, 64);
#endif
}

// ---------------------------------------------------------------------------
// one-hot [B*T, 126] fp32 -> TRANSPOSED index table obT[t*32 + b] (ushort).
// One wave per (b,t).
// ---------------------------------------------------------------------------
__global__ void onehot_to_idx_kernel(const float* __restrict__ x,
                                     unsigned short* __restrict__ obT, int total) {
    int wid  = (int)((blockIdx.x * blockDim.x + threadIdx.x) >> 6);
    int lane = threadIdx.x & 63;
    if (wid >= total) return;
    const float* row = x + (size_t)wid * NA;
    float v0 = row[lane];
    float v1 = (lane < NA - 64) ? row[64 + lane] : 0.0f;
    unsigned long long b0 = __ballot(v0 > 0.5f);
    unsigned long long b1 = __ballot(v1 > 0.5f);
    int idx = b0 ? (__ffsll(b0) - 1) : (64 + __ffsll(b1) - 1);
    if (lane == 0) {
        int b = wid / TLEN, t = wid - b * TLEN;
        obT[t * NBATCH + b] = (unsigned short)idx;
    }
}

// A-operand fragments: tile (jt, ic), lane l, elems e=0..3:
//   At[j][i] with j = jt*16 + (l&15), i = ic*16 + (l>>4)*4 + e
__global__ void pack_At_kernel(const float* __restrict__ A, uint2* __restrict__ Ah) {
    int idx = blockIdx.x * 256 + threadIdx.x;
    if (idx >= 81 * 64) return;
    int tile = idx >> 6, l = idx & 63;
    int jt = tile / 9, ic = tile % 9;
    int j  = jt * 16 + (l & 15);
    int i0 = ic * 16 + ((l >> 4) << 2);
    float v[4];
#pragma unroll
    for (int e = 0; e < 4; ++e) {
        int i = i0 + e;
        v[e] = (i < NS && j < NS) ? A[i * NS + j] : 0.0f;
    }
    h2 p01 = {(half_t)v[0], (half_t)v[1]};
    h2 p23 = {(half_t)v[2], (half_t)v[3]};
    Ah[idx] = make_uint2(bcu(p01), bcu(p23));
}

// emt[o][j] = f16(B[j][o]) for j<132, else 0.  [126][EMS]
__global__ void pack_em_kernel(const float* __restrict__ B, half_t* __restrict__ emt) {
    int idx = blockIdx.x * 256 + threadIdx.x;
    if (idx >= NA * EMS) return;
    int o = idx / EMS, j = idx % EMS;
    emt[idx] = (j < NS) ? (half_t)B[j * NA + o] : (half_t)0.f;
}

// I0 padded to 144 with zeros (f32)
__global__ void pack_I0_kernel(const float* __restrict__ I0, float* __restrict__ I0p) {
    int i = threadIdx.x;
    if (i < NSP) I0p[i] = (i < NS) ? I0[i] : 0.f;
}

// ---------------------------------------------------------------------------
// The serial scan. 2 blocks x 64 threads. Block handles batch cols
// [16*blk, 16*blk+15]; column = lane&15, row-groups = lane>>4.
// ---------------------------------------------------------------------------
__global__ __launch_bounds__(64)
__attribute__((amdgpu_waves_per_eu(1, 1)))
void hmm_mfma_kernel(
    const uint2* __restrict__ Ah,       // [81][64] A-frags
    const half_t* __restrict__ emt,     // [126][EMS]
    const float* __restrict__ I0p,      // [144]
    const unsigned short* __restrict__ obT,  // [TPAD][32]
    float* __restrict__ out)
{
    // 128 rows so a masked garbage o (<=127) still reads in-bounds
    __shared__ __align__(16) half_t sEm[128 * EMS];   // 37888 B

    const int l   = threadIdx.x;
    const int blk = blockIdx.x;
    const int g4  = (l >> 4) << 2;          // row-group offset (0,4,8,12)
    const int bc  = blk * 16 + (l & 15);    // this lane's batch column

    // stage emission table (126 rows) into LDS
    {
        const uint2* src = (const uint2*)emt;
        uint2* dst = (uint2*)sEm;
        for (int k = l; k < (NA * EMS) / 4; k += 64) dst[k] = src[k];
    }

    // resident A-operand fragments: 81 tiles x 2 VGPRs (AGPR exile harmless --
    // MFMA reads the A operand from AGPRs natively)
    half4 at_[9][9];
#pragma unroll
    for (int jt = 0; jt < 9; ++jt)
#pragma unroll
        for (int ic = 0; ic < 9; ++ic)
            at_[jt][ic] = __builtin_bit_cast(half4, Ah[(jt * 9 + ic) * 64 + l]);

    __syncthreads();                        // sEm staged

    const h2 ones = {(half_t)1.f, (half_t)1.f};
    const f32x4 Z4 = {0.f, 0.f, 0.f, 0.f};
    half4 y_[9];
    uint2 emc[9], emn[9];
    float zp, lp, ll = 0.f;

    // ---- t = 0: Y0[i][b] = 128 * I0[i] * em[i][o0(b)] ----
    {
        int o0 = obT[0 * NBATCH + bc] & 127;
#pragma unroll
        for (int ic = 0; ic < 9; ++ic)
            emc[ic] = *(const uint2*)&sEm[o0 * EMS + ic * 16 + g4];
        float zs = 0.f;
#pragma unroll
        for (int ic = 0; ic < 9; ++ic) {
            float4 iv = *(const float4*)&I0p[ic * 16 + g4];
            h2 e01 = bch2(emc[ic].x), e23 = bch2(emc[ic].y);
            h2 p01 = pkrtz(iv.x * (float)e01.x * 128.f, iv.y * (float)e01.y * 128.f);
            h2 p23 = pkrtz(iv.z * (float)e23.x * 128.f, iv.w * (float)e23.y * 128.f);
            y_[ic] = mk4(p01, p23);
            zs = FDOT2(p01, ones, FDOT2(p23, ones, zs));
        }
        zs = xadd16(zs);
        zs = xadd32(zs);
        zp = zs;
        lp = zs;                            // accumulates z_0
    }

    // emission for t = 1 + obs register pipeline (o_{t+1}, o_{t+2}, o_{t+3})
    int o_n1, o_n2, o_nf;
    {
        int o1 = obT[1 * NBATCH + bc] & 127;
#pragma unroll
        for (int ic = 0; ic < 9; ++ic)
            emc[ic] = *(const uint2*)&sEm[o1 * EMS + ic * 16 + g4];
        o_n1 = obT[2 * NBATCH + bc] & 127;
        o_n2 = obT[3 * NBATCH + bc] & 127;
        o_nf = obT[4 * NBATCH + bc] & 127;
    }

    // ---- main rolled loop: t = 1..9999 (body ~210 instrs, keep it rolled) ----
#pragma clang loop unroll(disable)
    for (int t = 1; t < TLEN; ++t) {
        // issue next-step emission reads first (no deps; waitcnt lands at use)
#pragma unroll
        for (int ic = 0; ic < 9; ++ic)
            emn[ic] = *(const uint2*)&sEm[o_n1 * EMS + ic * 16 + g4];

        const float gsc = 128.f * __builtin_amdgcn_rcpf(zp);
        const half_t gh = (half_t)gsc;
        const h2 g2 = {gh, gh};

        f32x4 d[9];
#pragma unroll
        for (int jt = 0; jt < 9; ++jt)
            d[jt] = __builtin_amdgcn_mfma_f32_16x16x16f16(
                        at_[jt][0], y_[0], Z4, 0, 0, 0);
#pragma unroll
        for (int ic = 1; ic < 9; ++ic) {
#pragma unroll
            for (int jt = 0; jt < 9; ++jt)
                d[jt] = __builtin_amdgcn_mfma_f32_16x16x16f16(
                            at_[jt][ic], y_[ic], d[jt], 0, 0, 0);
        }

        float za = 0.f, zb = 0.f, zc = 0.f, zd = 0.f;
#pragma unroll
        for (int jt = 0; jt < 9; ++jt) {
            h2 p01 = pkrtz(d[jt][0], d[jt][1]) * bch2(emc[jt].x) * g2;
            h2 p23 = pkrtz(d[jt][2], d[jt][3]) * bch2(emc[jt].y) * g2;
            y_[jt] = mk4(p01, p23);
            if (jt & 1) { zc = FDOT2(p01, ones, zc); zd = FDOT2(p23, ones, zd); }
            else        { za = FDOT2(p01, ones, za); zb = FDOT2(p23, ones, zb); }
        }
        float zs = (za + zb) + (zc + zd);
        zs = xadd16(zs);
        zs = xadd32(zs);
        zp = zs;
        lp *= zs;
        if ((t & 3) == 3) { ll += __logf(lp); lp = 1.f; }

        // rotate: emn -> emc, obs pipeline shift + refill (L2 load, 1-iter cover)
#pragma unroll
        for (int ic = 0; ic < 9; ++ic) emc[ic] = emn[ic];
        o_n1 = o_n2;
        o_n2 = o_nf;
        o_nf = obT[(t + 4) * NBATCH + bc] & 127;   // t+4 <= 10003 < TPAD
    }

    ll += __logf(lp);   // lp == 1 here (t=9999 folded); exactness guard

    if (l < 16) out[blk * 16 + l] = ll - 48520.302639196f;  // 10000*ln(128)
}

// ---------------------------------------------------------------------------
extern "C" void kernel_launch(void* const* d_in, const int* in_sizes, int n_in,
                              void* d_out, int out_size, void* d_ws, size_t ws_size,
                              hipStream_t stream) {
    const float* x  = (const float*)d_in[0];  // [32,10000,126] one-hot fp32
    const float* A  = (const float*)d_in[1];  // [132,132]
    const float* Bm = (const float*)d_in[2];  // [132,126]
    const float* I0 = (const float*)d_in[3];  // [132]
    float* out = (float*)d_out;               // [32] fp32

    char* ws = (char*)d_ws;
    unsigned short* obT = (unsigned short*)(ws + OBS_OFF);
    uint2*  Ah  = (uint2*)(ws + AT_OFF);
    half_t* emt = (half_t*)(ws + EM_OFF);
    float*  I0p = (float*)(ws + I0_OFF);

    const int total = NBATCH * TLEN;
    onehot_to_idx_kernel<<<(total + 3) / 4, 256, 0, stream>>>(x, obT, total);
    pack_At_kernel<<<(81 * 64 + 255) / 256, 256, 0, stream>>>(A, Ah);
    pack_em_kernel<<<(NA * EMS + 255) / 256, 256, 0, stream>>>(Bm, emt);
    pack_I0_kernel<<<1, NSP, 0, stream>>>(I0, I0p);
    hmm_mfma_kernel<<<2, 64, 0, stream>>>(Ah, emt, I0p, obT, out);
}

// Round 10
// 3223.814 us; speedup vs baseline: 2.7550x; 2.7550x over previous
//
#include <hip/hip_runtime.h>

// ---------------------------------------------------------------------------
// Scaled HMM forward, B=32 rows, T=10000 serial steps, N=132 states.
// ROUND-10 REDESIGN: matrix-product scan. Rounds 1-9 were a serial chain on
// <=2 CUs; ~1200cy/step of exposed latency survived every body structure.
// Now: C=8 chunks x 32 batch = 256 blocks (1/CU). Each block computes its
// chunk operator Q_c = (prod_t M_t)^T, M_t = A diag(b_t), via the VERIFIED
// round-8 fragment recurrence applied to 9 column panels:
//     Q_new = diag(b_t) (At @ Q),  At = A^T in MFMA A-frags (registers)
// 16x16x16f16 layout identity: D rows == B k-slots per lane, so each step's
// output fragments ARE the next step's B operands. Per-COLUMN normalization
// (xadd16/32 gives per-lane=per-column sums) with exact log bookkeeping:
//   stored Q = true Q * e^{sigma_col},  sigma_col = len*ln128 - sum ln(z_col)
// A combine kernel chains alpha through the 8 operators in f32 log-space.
// Fallback: if ws_size < ~11.5MB, run the verified round-8 serial kernel.
// ---------------------------------------------------------------------------

typedef _Float16 half_t;
typedef half_t h2 __attribute__((ext_vector_type(2)));
typedef half_t half4 __attribute__((ext_vector_type(4)));
typedef float  f32x4 __attribute__((ext_vector_type(4)));
typedef unsigned int uint2v __attribute__((ext_vector_type(2)));

#define FDOT2(a, b, acc) __builtin_amdgcn_fdot2((a), (b), (acc), false)

#define NS 132
#define NA 126
#define NSP 144        // padded states: 9 tiles of 16
#define EMS 148        // em row stride in halves (296 B, bank-spread)
#define TLEN 10000
#define NBATCH 32
#define NCHUNK 8
#define LN128 4.852030263919617f

// ws layout (bytes)
#define OBS_OFF 0                       // 32*10000*2 + pad = 640064
#define AT_OFF  640064                  // 81*64*8 = 41472
#define EM_OFF  (AT_OFF + 81*64*8)      // 681536; 126*148*2 = 37296
#define I0_OFF  (EM_OFF + NA*EMS*2)     // 718832; 576 (fallback only)
#define SIG_OFF (I0_OFF + 576)          // 719408; 32*8*144*4 = 147456
#define QT_OFF  866880                  // aligned; 32*8*144*144*2 = 10616832
#define WS_NEED (QT_OFF + NBATCH*NCHUNK*NSP*NSP*2)   // 11,483,712

static __device__ __forceinline__ h2 bch2(unsigned int u) {
    return __builtin_bit_cast(h2, u);
}
static __device__ __forceinline__ unsigned int bcu(h2 v) {
    return __builtin_bit_cast(unsigned int, v);
}
static __device__ __forceinline__ h2 pkrtz(float a, float b) {
    return __builtin_bit_cast(h2, __builtin_amdgcn_cvt_pkrtz(a, b));
}
static __device__ __forceinline__ half4 mk4(h2 a, h2 b) {
    uint2 u = make_uint2(bcu(a), bcu(b));
    return __builtin_bit_cast(half4, u);
}
static __device__ __forceinline__ float xadd16(float v) {
#if __has_builtin(__builtin_amdgcn_permlane16_swap)
    uint2v r = __builtin_amdgcn_permlane16_swap(
        __builtin_bit_cast(unsigned int, v), __builtin_bit_cast(unsigned int, v),
        false, false);
    return __builtin_bit_cast(float, r[0]) + __builtin_bit_cast(float, r[1]);
#else
    return v + __shfl_xor(v, 16, 64);
#endif
}
static __device__ __forceinline__ float xadd32(float v) {
#if __has_builtin(__builtin_amdgcn_permlane32_swap)
    uint2v r = __builtin_amdgcn_permlane32_swap(
        __builtin_bit_cast(unsigned int, v), __builtin_bit_cast(unsigned int, v),
        false, false);
    return __builtin_bit_cast(float, r[0]) + __builtin_bit_cast(float, r[1]);
#else
    return v + __shfl_xor(v, 32, 64);
#endif
}
static __device__ __forceinline__ float wsum(float v) {
#pragma unroll
    for (int o = 32; o; o >>= 1) v += __shfl_xor(v, o, 64);
    return v;
}
static __device__ __forceinline__ float wmin(float v) {
#pragma unroll
    for (int o = 32; o; o >>= 1) v = fminf(v, __shfl_xor(v, o, 64));
    return v;
}

// ---------------------------------------------------------------------------
// one-hot [B*T, 126] fp32 -> index obs[b*T + t] (ushort). One wave per (b,t).
// ---------------------------------------------------------------------------
__global__ void onehot_to_idx_kernel(const float* __restrict__ x,
                                     unsigned short* __restrict__ obs, int total) {
    int wid  = (int)((blockIdx.x * blockDim.x + threadIdx.x) >> 6);
    int lane = threadIdx.x & 63;
    if (wid >= total) return;
    const float* row = x + (size_t)wid * NA;
    float v0 = row[lane];
    float v1 = (lane < NA - 64) ? row[64 + lane] : 0.0f;
    unsigned long long b0 = __ballot(v0 > 0.5f);
    unsigned long long b1 = __ballot(v1 > 0.5f);
    int idx = b0 ? (__ffsll(b0) - 1) : (64 + __ffsll(b1) - 1);
    if (lane == 0) obs[wid] = (unsigned short)idx;
}

// A-operand fragments: tile (jt, ic), lane l, elems e=0..3:
//   At[j][i] = A[i][j] with j = jt*16 + (l&15), i = ic*16 + (l>>4)*4 + e
__global__ void pack_At_kernel(const float* __restrict__ A, uint2* __restrict__ Ah) {
    int idx = blockIdx.x * 256 + threadIdx.x;
    if (idx >= 81 * 64) return;
    int tile = idx >> 6, l = idx & 63;
    int jt = tile / 9, ic = tile % 9;
    int j  = jt * 16 + (l & 15);
    int i0 = ic * 16 + ((l >> 4) << 2);
    float v[4];
#pragma unroll
    for (int e = 0; e < 4; ++e) {
        int i = i0 + e;
        v[e] = (i < NS && j < NS) ? A[i * NS + j] : 0.0f;
    }
    h2 p01 = {(half_t)v[0], (half_t)v[1]};
    h2 p23 = {(half_t)v[2], (half_t)v[3]};
    Ah[idx] = make_uint2(bcu(p01), bcu(p23));
}

// emt[o][j] = f16(B[j][o]) for j<132, else 0.  [126][EMS]
__global__ void pack_em_kernel(const float* __restrict__ B, half_t* __restrict__ emt) {
    int idx = blockIdx.x * 256 + threadIdx.x;
    if (idx >= NA * EMS) return;
    int o = idx / EMS, j = idx % EMS;
    emt[idx] = (j < NS) ? (half_t)B[j * NA + o] : (half_t)0.f;
}

// I0 padded to 144 (fallback path only)
__global__ void pack_I0_kernel(const float* __restrict__ I0, float* __restrict__ I0p) {
    int i = threadIdx.x;
    if (i < NSP) I0p[i] = (i < NS) ? I0[i] : 0.f;
}

// ---------------------------------------------------------------------------
// FAST PATH kernel A: chunk operators. 256 blocks x 192 threads (3 waves).
// Block (b = blk>>3, c = blk&7); wave w owns panels 3w..3w+2 (16 cols each).
// ---------------------------------------------------------------------------
__global__ __launch_bounds__(192)
__attribute__((amdgpu_waves_per_eu(1, 1)))
void hmm_chunk_kernel(
    const uint2* __restrict__ Ah,       // [81][64] A-frags
    const half_t* __restrict__ emt,     // [126][EMS]
    const unsigned short* __restrict__ obs,  // [32][10000]
    half_t* __restrict__ Qt,            // [32*8][144 cols][144 rows] f16
    float* __restrict__ Sig)            // [32*8][144] per-column log-scale
{
    __shared__ __align__(16) half_t sEm[128 * EMS];

    const int tid = threadIdx.x;
    const int l = tid & 63, w = tid >> 6;
    const int b = blockIdx.x >> 3, c = blockIdx.x & 7;
    const int g4 = (l >> 4) << 2;

    for (int k = tid; k < (NA * EMS) / 4; k += 192)
        ((uint2*)sEm)[k] = ((const uint2*)emt)[k];

    half4 at_[9][9];
#pragma unroll
    for (int jt = 0; jt < 9; ++jt)
#pragma unroll
        for (int ic = 0; ic < 9; ++ic)
            at_[jt][ic] = __builtin_bit_cast(half4, Ah[(jt * 9 + ic) * 64 + l]);

    __syncthreads();

    // Q = Identity fragments for this wave's 3 panels
    half4 q[3][9];
#pragma unroll
    for (int pp = 0; pp < 3; ++pp) {
        const int colg = (3 * w + pp) * 16 + (l & 15);
#pragma unroll
        for (int ic = 0; ic < 9; ++ic) {
            const int k0 = ic * 16 + g4;
            h2 a01 = {(half_t)(k0     == colg ? 1.f : 0.f),
                      (half_t)(k0 + 1 == colg ? 1.f : 0.f)};
            h2 a23 = {(half_t)(k0 + 2 == colg ? 1.f : 0.f),
                      (half_t)(k0 + 3 == colg ? 1.f : 0.f)};
            q[pp][ic] = mk4(a01, a23);
        }
    }

    const unsigned short* ob = obs + (size_t)b * TLEN;
    const int t0  = 1 + 1250 * c;
    const int len = (c == 7) ? 1249 : 1250;

    uint2 emc[9], emn[9];
    {
        int o = ob[t0];
#pragma unroll
        for (int ic = 0; ic < 9; ++ic)
            emc[ic] = *(const uint2*)&sEm[o * EMS + ic * 16 + g4];
    }
    int o_n1 = ob[(t0 + 1 > TLEN - 1) ? TLEN - 1 : t0 + 1];
    int o_n2 = ob[(t0 + 2 > TLEN - 1) ? TLEN - 1 : t0 + 2];
    int o_nf = ob[(t0 + 3 > TLEN - 1) ? TLEN - 1 : t0 + 3];

    float zp[3]   = {1.f, 1.f, 1.f};   // per-lane = per-COLUMN running sums
    float lp[3]   = {1.f, 1.f, 1.f};
    float sraw[3] = {0.f, 0.f, 0.f};
    const h2 ones = {(half_t)1.f, (half_t)1.f};
    const f32x4 Z4 = {0.f, 0.f, 0.f, 0.f};

#pragma clang loop unroll(disable)
    for (int n = 0; n < len; ++n) {
        // issue next-step emission reads (independent; waitcnt lands at use)
#pragma unroll
        for (int ic = 0; ic < 9; ++ic)
            emn[ic] = *(const uint2*)&sEm[o_n1 * EMS + ic * 16 + g4];

#pragma unroll
        for (int pp = 0; pp < 3; ++pp) {
            const float gsc = 128.f * __builtin_amdgcn_rcpf(zp[pp]);
            lp[pp] *= zp[pp];            // record the applied divisor
            const half_t gh = (half_t)gsc;
            const h2 g2 = {gh, gh};

            f32x4 d[9];
#pragma unroll
            for (int jt = 0; jt < 9; ++jt)
                d[jt] = __builtin_amdgcn_mfma_f32_16x16x16f16(
                            at_[jt][0], q[pp][0], Z4, 0, 0, 0);
#pragma unroll
            for (int ic = 1; ic < 9; ++ic)
#pragma unroll
                for (int jt = 0; jt < 9; ++jt)
                    d[jt] = __builtin_amdgcn_mfma_f32_16x16x16f16(
                                at_[jt][ic], q[pp][ic], d[jt], 0, 0, 0);

            float za = 0.f, zb = 0.f, zc_ = 0.f, zd_ = 0.f;
#pragma unroll
            for (int jt = 0; jt < 9; ++jt) {
                h2 p01 = pkrtz(d[jt][0], d[jt][1]) * bch2(emc[jt].x) * g2;
                h2 p23 = pkrtz(d[jt][2], d[jt][3]) * bch2(emc[jt].y) * g2;
                q[pp][jt] = mk4(p01, p23);
                if (jt & 1) { zc_ = FDOT2(p01, ones, zc_); zd_ = FDOT2(p23, ones, zd_); }
                else        { za  = FDOT2(p01, ones, za);  zb  = FDOT2(p23, ones, zb); }
            }
            float zs = (za + zb) + (zc_ + zd_);
            zs = xadd16(zs);             // sums the 4 row-group lanes of this
            zs = xadd32(zs);             // lane's column -> full column sum
            zp[pp] = fmaxf(zs, 1e-30f);  // dead-column guard (cols >= 132)
        }
        if ((n & 3) == 3) {
#pragma unroll
            for (int pp = 0; pp < 3; ++pp) { sraw[pp] += __logf(lp[pp]); lp[pp] = 1.f; }
        }
#pragma unroll
        for (int ic = 0; ic < 9; ++ic) emc[ic] = emn[ic];
        o_n1 = o_n2; o_n2 = o_nf;
        int tn = t0 + n + 4;
        o_nf = ob[(tn > TLEN - 1) ? TLEN - 1 : tn];
    }
#pragma unroll
    for (int pp = 0; pp < 3; ++pp) sraw[pp] += __logf(lp[pp]);

    // store per-column sigma and the Q panels ([col][row] layout, f16)
    const int bc = b * NCHUNK + c;
#pragma unroll
    for (int pp = 0; pp < 3; ++pp) {
        if (l < 16)
            Sig[bc * NSP + (3 * w + pp) * 16 + l] = (float)len * LN128 - sraw[pp];
#pragma unroll
        for (int ic = 0; ic < 9; ++ic) {
            size_t off = ((size_t)bc * NSP + (3 * w + pp) * 16 + (l & 15)) * NSP
                         + ic * 16 + g4;
            *(uint2*)(Qt + off) = __builtin_bit_cast(uint2, q[pp][ic]);
        }
    }
}

// ---------------------------------------------------------------------------
// FAST PATH kernel B: chain alpha through the 8 chunk operators (f32,
// log-space). 32 blocks x 64 threads; lane holds states 2l, 2l+1 (+extras).
// ---------------------------------------------------------------------------
__global__ __launch_bounds__(64)
void hmm_combine_kernel(
    const half_t* __restrict__ Qt,
    const float* __restrict__ Sig,
    const float* __restrict__ Bm,      // original f32 [132][126]
    const float* __restrict__ I0,
    const unsigned short* __restrict__ obs,
    float* __restrict__ out)
{
    __shared__ float awL[NS + 4];
    const int l = threadIdx.x, b = blockIdx.x;
    const int j0 = 2 * l;

    int o0 = obs[(size_t)b * TLEN];
    float a0 = I0[j0]     * Bm[j0 * NA + o0];
    float a1 = I0[j0 + 1] * Bm[(j0 + 1) * NA + o0];
    float ax0 = 0.f, ax1 = 0.f;
    if (l < 2) {
        int jx = 128 + 2 * l;
        ax0 = I0[jx]     * Bm[jx * NA + o0];
        ax1 = I0[jx + 1] * Bm[(jx + 1) * NA + o0];
    }
    float S = wsum(a0 + a1 + ax0 + ax1);
    float ll = __logf(S);
    float inv = 1.f / S;
    float an0 = a0 * inv, an1 = a1 * inv, anx0 = ax0 * inv, anx1 = ax1 * inv;

    for (int c = 0; c < NCHUNK; ++c) {
        const float* sg = Sig + (size_t)(b * NCHUNK + c) * NSP;
        float s0 = sg[j0], s1 = sg[j0 + 1];
        float m = fminf(s0, s1);
        float sx0 = 0.f, sx1 = 0.f;
        if (l < 2) {
            sx0 = sg[128 + 2 * l]; sx1 = sg[129 + 2 * l];
            m = fminf(m, fminf(sx0, sx1));
        }
        float smin = wmin(m);

        awL[j0]     = an0 * __expf(smin - s0);
        awL[j0 + 1] = an1 * __expf(smin - s1);
        if (l < 2) {
            awL[128 + 2 * l] = anx0 * __expf(smin - sx0);
            awL[129 + 2 * l] = anx1 * __expf(smin - sx1);
        }
        __syncthreads();

        const half_t* Qc = Qt + (size_t)(b * NCHUNK + c) * NSP * NSP;
        float y0 = 0.f, y1 = 0.f, yx0 = 0.f, yx1 = 0.f;
        for (int i = 0; i < NS; ++i) {
            float av = awL[i];
            unsigned u = *(const unsigned*)(Qc + (size_t)i * NSP + j0);
            h2 h = bch2(u);
            y0 += av * (float)h.x;
            y1 += av * (float)h.y;
            if (l < 2) {
                unsigned ux = *(const unsigned*)(Qc + (size_t)i * NSP + 128 + 2 * l);
                h2 hx = bch2(ux);
                yx0 += av * (float)hx.x;
                yx1 += av * (float)hx.y;
            }
        }
        float Sc = wsum(y0 + y1 + yx0 + yx1);
        ll += __logf(Sc) - smin;
        float inv2 = 1.f / Sc;
        an0 = y0 * inv2; an1 = y1 * inv2; anx0 = yx0 * inv2; anx1 = yx1 * inv2;
        __syncthreads();
    }
    if (l == 0) out[b] = ll;
}

// ---------------------------------------------------------------------------
// FALLBACK: round-8 serial kernel (verified, 7.54 ms) for small ws_size.
// ---------------------------------------------------------------------------
__global__ __launch_bounds__(64)
__attribute__((amdgpu_waves_per_eu(1, 1)))
void hmm_mfma_kernel(
    const uint2* __restrict__ Ah, const half_t* __restrict__ emt,
    const float* __restrict__ I0p, const unsigned short* __restrict__ obs,
    float* __restrict__ out)
{
    __shared__ __align__(16) half_t sEm[128 * EMS];
    const int l = threadIdx.x, blk = blockIdx.x;
    const int g4 = (l >> 4) << 2;
    for (int k = l; k < (NA * EMS) / 4; k += 64)
        ((uint2*)sEm)[k] = ((const uint2*)emt)[k];
    half4 at_[9][9];
#pragma unroll
    for (int jt = 0; jt < 9; ++jt)
#pragma unroll
        for (int ic = 0; ic < 9; ++ic)
            at_[jt][ic] = __builtin_bit_cast(half4, Ah[(jt * 9 + ic) * 64 + l]);
    const unsigned short* ob = obs + (size_t)(blk * 16 + (l & 15)) * TLEN;
    uint4 pk = *(const uint4*)ob;
    __syncthreads();
    const h2 ones = {(half_t)1.f, (half_t)1.f};
    const f32x4 Z4 = {0.f, 0.f, 0.f, 0.f};
    half4 y_[9];
    uint2 emc[9], emn[9];
    float zp, lp, ll = 0.f;
    {
        int o0 = pk.x & 127;
#pragma unroll
        for (int ic = 0; ic < 9; ++ic)
            emc[ic] = *(const uint2*)&sEm[o0 * EMS + ic * 16 + g4];
        float zs = 0.f;
#pragma unroll
        for (int ic = 0; ic < 9; ++ic) {
            float4 iv = *(const float4*)&I0p[ic * 16 + g4];
            h2 e01 = bch2(emc[ic].x), e23 = bch2(emc[ic].y);
            h2 p01 = pkrtz(iv.x * (float)e01.x * 128.f, iv.y * (float)e01.y * 128.f);
            h2 p23 = pkrtz(iv.z * (float)e23.x * 128.f, iv.w * (float)e23.y * 128.f);
            y_[ic] = mk4(p01, p23);
            zs = FDOT2(p01, ones, FDOT2(p23, ones, zs));
        }
        zs = xadd16(zs); zs = xadd32(zs);
        zp = zs; lp = zs;
        int o1 = (pk.x >> 16) & 127;
#pragma unroll
        for (int ic = 0; ic < 9; ++ic)
            emc[ic] = *(const uint2*)&sEm[o1 * EMS + ic * 16 + g4];
    }
#define GETO(P, K) ((int)(((&(P).x)[(K) >> 1] >> (((K) & 1) * 16)) & 127))
#define STEP8(O_NEXT, FOLD) do {                                              \
    const int _on = (O_NEXT);                                                 \
    _Pragma("unroll")                                                         \
    for (int ic = 0; ic < 9; ++ic)                                            \
        emn[ic] = *(const uint2*)&sEm[_on * EMS + ic * 16 + g4];              \
    const float gsc = 128.f * __builtin_amdgcn_rcpf(zp);                      \
    const half_t gh = (half_t)gsc;                                            \
    const h2 g2 = {gh, gh};                                                   \
    f32x4 d[9];                                                               \
    _Pragma("unroll")                                                         \
    for (int jt = 0; jt < 9; ++jt)                                            \
        d[jt] = __builtin_amdgcn_mfma_f32_16x16x16f16(at_[jt][0], y_[0], Z4, 0, 0, 0); \
    _Pragma("unroll")                                                         \
    for (int ic = 1; ic < 9; ++ic) {                                          \
        _Pragma("unroll")                                                     \
        for (int jt = 0; jt < 9; ++jt)                                        \
            d[jt] = __builtin_amdgcn_mfma_f32_16x16x16f16(at_[jt][ic], y_[ic], d[jt], 0, 0, 0); \
    }                                                                         \
    float za = 0.f, zb = 0.f, zc = 0.f, zd = 0.f;                             \
    _Pragma("unroll")                                                         \
    for (int jt = 0; jt < 9; ++jt) {                                          \
        h2 p01 = pkrtz(d[jt][0], d[jt][1]) * bch2(emc[jt].x) * g2;            \
        h2 p23 = pkrtz(d[jt][2], d[jt][3]) * bch2(emc[jt].y) * g2;            \
        y_[jt] = mk4(p01, p23);                                               \
        if (jt & 1) { zc = FDOT2(p01, ones, zc); zd = FDOT2(p23, ones, zd); } \
        else        { za = FDOT2(p01, ones, za); zb = FDOT2(p23, ones, zb); } \
    }                                                                         \
    float zs = (za + zb) + (zc + zd);                                         \
    zs = xadd16(zs); zs = xadd32(zs);                                         \
    zp = zs; lp *= zs;                                                        \
    if (FOLD) { ll += __logf(lp); lp = 1.f; }                                 \
    _Pragma("unroll")                                                         \
    for (int ic = 0; ic < 9; ++ic) emc[ic] = emn[ic];                         \
} while (0)
    {
        uint4 pn = *(const uint4*)(ob + 8);
#pragma unroll
        for (int k = 1; k < 8; ++k) {
            int on = (k < 7) ? GETO(pk, k + 1) : (int)(pn.x & 127);
            STEP8(on, (k & 3) == 3);
        }
        pk = pn;
    }
    for (int c = 1; c < 1250; ++c) {
        uint4 pn = *(const uint4*)(ob + 8 * (c + 1));
#pragma unroll
        for (int k = 0; k < 8; ++k) {
            int on = (k < 7) ? GETO(pk, k + 1) : (int)(pn.x & 127);
            STEP8(on, (k & 3) == 3);
        }
        pk = pn;
    }
    if (l < 16) out[blk * 16 + l] = ll - 48520.302639196f;
}

// ---------------------------------------------------------------------------
extern "C" void kernel_launch(void* const* d_in, const int* in_sizes, int n_in,
                              void* d_out, int out_size, void* d_ws, size_t ws_size,
                              hipStream_t stream) {
    const float* x  = (const float*)d_in[0];  // [32,10000,126] one-hot fp32
    const float* A  = (const float*)d_in[1];  // [132,132]
    const float* Bm = (const float*)d_in[2];  // [132,126]
    const float* I0 = (const float*)d_in[3];  // [132]
    float* out = (float*)d_out;               // [32] fp32

    char* ws = (char*)d_ws;
    unsigned short* obs = (unsigned short*)(ws + OBS_OFF);
    uint2*  Ah  = (uint2*)(ws + AT_OFF);
    half_t* emt = (half_t*)(ws + EM_OFF);
    float*  I0p = (float*)(ws + I0_OFF);
    float*  Sig = (float*)(ws + SIG_OFF);
    half_t* Qt  = (half_t*)(ws + QT_OFF);

    const int total = NBATCH * TLEN;
    onehot_to_idx_kernel<<<(total + 3) / 4, 256, 0, stream>>>(x, obs, total);
    pack_At_kernel<<<(81 * 64 + 255) / 256, 256, 0, stream>>>(A, Ah);
    pack_em_kernel<<<(NA * EMS + 255) / 256, 256, 0, stream>>>(Bm, emt);

    if (ws_size >= (size_t)WS_NEED) {
        hmm_chunk_kernel<<<NBATCH * NCHUNK, 192, 0, stream>>>(Ah, emt, obs, Qt, Sig);
        hmm_combine_kernel<<<NBATCH, 64, 0, stream>>>(Qt, Sig, Bm, I0, obs, out);
    } else {
        pack_I0_kernel<<<1, NSP, 0, stream>>>(I0, I0p);
        hmm_mfma_kernel<<<2, 64, 0, stream>>>(Ah, emt, I0p, obs, out);
    }
}

// Round 11
// 3122.458 us; speedup vs baseline: 2.8445x; 1.0325x over previous
//
#include <hip/hip_runtime.h>

// ---------------------------------------------------------------------------
// Scaled HMM forward, B=32 rows, T=10000 serial steps, N=132 states.
// ROUND-11: round-10 chunked matrix-product scan (verified absmax 0.0), with
// ONE PANEL PER WAVE. Round 10 was register-strangled: 334 regs/wave (3
// panels) -> 1 wave/SIMD, panels serialized, d-chains collapsed to dependent
// MFMA runs (~1460cy/panel stall). One panel/wave ~= 250 regs ->
// __launch_bounds__(192,2) caps at 256 -> 2 waves/SIMD, 9 independent d[jt]
// chains stay live (reuse distance 36cy >= MFMA latency).
// Block = (b, chunk c, panel-group pg) x 3 waves; wave w owns panel pg*3+w.
// C=16 chunks (runtime-tiered to C=8 if ws < need; round 10 proved 11.48MB).
// Math identical to round 10: Q_new = diag(em_o) (At @ Q) per column panel,
// per-column 1-lag normalization g=128*rcp(zp), exact log bookkeeping.
// ---------------------------------------------------------------------------

typedef _Float16 half_t;
typedef half_t h2 __attribute__((ext_vector_type(2)));
typedef half_t half4 __attribute__((ext_vector_type(4)));
typedef float  f32x4 __attribute__((ext_vector_type(4)));
typedef unsigned int uint2v __attribute__((ext_vector_type(2)));

#define FDOT2(a, b, acc) __builtin_amdgcn_fdot2((a), (b), (acc), false)

#define NS 132
#define NA 126
#define NSP 144        // padded states: 9 tiles of 16
#define EMS 148        // em row stride in halves (296 B, bank-spread)
#define TLEN 10000
#define NBATCH 32
#define LN128 4.852030263919617f

// ws layout (bytes)
#define OBS_OFF 0                    // 32*10000*2 = 640000 (+pad)
#define AT_OFF  640064               // 81*64*8 = 41472
#define EM_OFF  (AT_OFF + 81*64*8)   // 681536; 126*148*2 = 37296 -> ends 718832
#define SIG_OFF 718848               // 64-aligned

static __device__ __forceinline__ h2 bch2(unsigned int u) {
    return __builtin_bit_cast(h2, u);
}
static __device__ __forceinline__ unsigned int bcu(h2 v) {
    return __builtin_bit_cast(unsigned int, v);
}
static __device__ __forceinline__ h2 pkrtz(float a, float b) {
    return __builtin_bit_cast(h2, __builtin_amdgcn_cvt_pkrtz(a, b));
}
static __device__ __forceinline__ half4 mk4(h2 a, h2 b) {
    uint2 u = make_uint2(bcu(a), bcu(b));
    return __builtin_bit_cast(half4, u);
}
static __device__ __forceinline__ float xadd16(float v) {
#if __has_builtin(__builtin_amdgcn_permlane16_swap)
    uint2v r = __builtin_amdgcn_permlane16_swap(
        __builtin_bit_cast(unsigned int, v), __builtin_bit_cast(unsigned int, v),
        false, false);
    return __builtin_bit_cast(float, r[0]) + __builtin_bit_cast(float, r[1]);
#else
    return v + __shfl_xor(v, 16, 64);
#endif
}
static __device__ __forceinline__ float xadd32(float v) {
#if __has_builtin(__builtin_amdgcn_permlane32_swap)
    uint2v r = __builtin_amdgcn_permlane32_swap(
        __builtin_bit_cast(unsigned int, v), __builtin_bit_cast(unsigned int, v),
        false, false);
    return __builtin_bit_cast(float, r[0]) + __builtin_bit_cast(float, r[1]);
#else
    return v + __shfl_xor(v, 32, 64);
#endif
}
static __device__ __forceinline__ float wsum(float v) {
#pragma unroll
    for (int o = 32; o; o >>= 1) v += __shfl_xor(v, o, 64);
    return v;
}
static __device__ __forceinline__ float wmin(float v) {
#pragma unroll
    for (int o = 32; o; o >>= 1) v = fminf(v, __shfl_xor(v, o, 64));
    return v;
}

// ---------------------------------------------------------------------------
// one-hot [B*T, 126] fp32 -> index obs[b*T + t] (ushort). One wave per (b,t).
// ---------------------------------------------------------------------------
__global__ void onehot_to_idx_kernel(const float* __restrict__ x,
                                     unsigned short* __restrict__ obs, int total) {
    int wid  = (int)((blockIdx.x * blockDim.x + threadIdx.x) >> 6);
    int lane = threadIdx.x & 63;
    if (wid >= total) return;
    const float* row = x + (size_t)wid * NA;
    float v0 = row[lane];
    float v1 = (lane < NA - 64) ? row[64 + lane] : 0.0f;
    unsigned long long b0 = __ballot(v0 > 0.5f);
    unsigned long long b1 = __ballot(v1 > 0.5f);
    int idx = b0 ? (__ffsll(b0) - 1) : (64 + __ffsll(b1) - 1);
    if (lane == 0) obs[wid] = (unsigned short)idx;
}

// A-operand fragments: tile (jt, ic), lane l, elems e=0..3:
//   At[j][i] = A[i][j] with j = jt*16 + (l&15), i = ic*16 + (l>>4)*4 + e
__global__ void pack_At_kernel(const float* __restrict__ A, uint2* __restrict__ Ah) {
    int idx = blockIdx.x * 256 + threadIdx.x;
    if (idx >= 81 * 64) return;
    int tile = idx >> 6, l = idx & 63;
    int jt = tile / 9, ic = tile % 9;
    int j  = jt * 16 + (l & 15);
    int i0 = ic * 16 + ((l >> 4) << 2);
    float v[4];
#pragma unroll
    for (int e = 0; e < 4; ++e) {
        int i = i0 + e;
        v[e] = (i < NS && j < NS) ? A[i * NS + j] : 0.0f;
    }
    h2 p01 = {(half_t)v[0], (half_t)v[1]};
    h2 p23 = {(half_t)v[2], (half_t)v[3]};
    Ah[idx] = make_uint2(bcu(p01), bcu(p23));
}

// emt[o][j] = f16(B[j][o]) for j<132, else 0.  [126][EMS]
__global__ void pack_em_kernel(const float* __restrict__ B, half_t* __restrict__ emt) {
    int idx = blockIdx.x * 256 + threadIdx.x;
    if (idx >= NA * EMS) return;
    int o = idx / EMS, j = idx % EMS;
    emt[idx] = (j < NS) ? (half_t)B[j * NA + o] : (half_t)0.f;
}

// ---------------------------------------------------------------------------
// Chunk operators: grid = 32 b x C chunks x 3 panel-groups, 192 threads.
// Wave w of block (b,c,pg) evolves panel p = pg*3+w (16 columns of Q).
// ---------------------------------------------------------------------------
__global__ __launch_bounds__(192, 2)
void hmm_chunk_kernel(
    const uint2* __restrict__ Ah,       // [81][64] A-frags
    const half_t* __restrict__ emt,     // [126][EMS]
    const unsigned short* __restrict__ obs,  // [32][10000]
    half_t* __restrict__ Qt,            // [32*C][144 cols][144 rows] f16
    float* __restrict__ Sig,            // [32*C][144] per-column log-scale
    int nchunk, int lenbase)
{
    __shared__ __align__(16) half_t sEm[128 * EMS];

    const int tid = threadIdx.x;
    const int l = tid & 63, w = tid >> 6;
    const int blk = blockIdx.x;
    const int pg = blk % 3;
    const int c  = (blk / 3) % nchunk;
    const int b  = blk / (3 * nchunk);
    const int p  = pg * 3 + w;              // this wave's panel (0..8)
    const int g4 = (l >> 4) << 2;

    for (int k = tid; k < (NA * EMS) / 4; k += 192)
        ((uint2*)sEm)[k] = ((const uint2*)emt)[k];

    // full At resident (162 regs; AGPR exile fine -- MFMA A-operand)
    half4 at_[9][9];
#pragma unroll
    for (int jt = 0; jt < 9; ++jt)
#pragma unroll
        for (int ic = 0; ic < 9; ++ic)
            at_[jt][ic] = __builtin_bit_cast(half4, Ah[(jt * 9 + ic) * 64 + l]);

    __syncthreads();

    // Q = identity fragments for this wave's panel
    half4 q[9];
    {
        const int colg = p * 16 + (l & 15);
#pragma unroll
        for (int ic = 0; ic < 9; ++ic) {
            const int k0 = ic * 16 + g4;
            h2 a01 = {(half_t)(k0     == colg ? 1.f : 0.f),
                      (half_t)(k0 + 1 == colg ? 1.f : 0.f)};
            h2 a23 = {(half_t)(k0 + 2 == colg ? 1.f : 0.f),
                      (half_t)(k0 + 3 == colg ? 1.f : 0.f)};
            q[ic] = mk4(a01, a23);
        }
    }

    const unsigned short* ob = obs + (size_t)b * TLEN;
    const int t0 = 1 + lenbase * c;
    int len = (TLEN - 1) - lenbase * c;
    if (len > lenbase) len = lenbase;

    // observation register pipeline (current + 3 ahead, clamped)
    int o_c  = ob[t0];
    int o_n1 = ob[(t0 + 1 <= TLEN - 1) ? t0 + 1 : TLEN - 1];
    int o_n2 = ob[(t0 + 2 <= TLEN - 1) ? t0 + 2 : TLEN - 1];
    int o_n3 = ob[(t0 + 3 <= TLEN - 1) ? t0 + 3 : TLEN - 1];

    float zp = 1.f, lp = 1.f, sraw = 0.f;
    const h2 ones = {(half_t)1.f, (half_t)1.f};
    const f32x4 Z4 = {0.f, 0.f, 0.f, 0.f};

#pragma clang loop unroll(disable)
    for (int n = 0; n < len; ++n) {
        // em reads for THIS step issued before the MFMA block (latency hides
        // under 81-MFMA issue; first consumer is ~350cy downstream)
        uint2 emc[9];
#pragma unroll
        for (int ic = 0; ic < 9; ++ic)
            emc[ic] = *(const uint2*)&sEm[o_c * EMS + ic * 16 + g4];

        const float gsc = 128.f * __builtin_amdgcn_rcpf(zp);
        lp *= zp;                     // record the applied divisor
        const half_t gh = (half_t)gsc;
        const h2 g2 = {gh, gh};

        f32x4 d[9];
#pragma unroll
        for (int jt = 0; jt < 9; ++jt)
            d[jt] = __builtin_amdgcn_mfma_f32_16x16x16f16(
                        at_[jt][0], q[0], Z4, 0, 0, 0);
#pragma unroll
        for (int ic = 1; ic < 9; ++ic)
#pragma unroll
            for (int jt = 0; jt < 9; ++jt)
                d[jt] = __builtin_amdgcn_mfma_f32_16x16x16f16(
                            at_[jt][ic], q[ic], d[jt], 0, 0, 0);

        float za = 0.f, zb = 0.f, zc_ = 0.f, zd_ = 0.f;
#pragma unroll
        for (int jt = 0; jt < 9; ++jt) {
            h2 p01 = pkrtz(d[jt][0], d[jt][1]) * bch2(emc[jt].x) * g2;
            h2 p23 = pkrtz(d[jt][2], d[jt][3]) * bch2(emc[jt].y) * g2;
            q[jt] = mk4(p01, p23);
            if (jt & 1) { zc_ = FDOT2(p01, ones, zc_); zd_ = FDOT2(p23, ones, zd_); }
            else        { za  = FDOT2(p01, ones, za);  zb  = FDOT2(p23, ones, zb); }
        }
        float zs = (za + zb) + (zc_ + zd_);
        zs = xadd16(zs);              // 4 row-group lanes of this column
        zs = xadd32(zs);
        zp = fmaxf(zs, 1e-30f);       // dead-column guard (cols >= 132)

        if ((n & 3) == 3) { sraw += __logf(lp); lp = 1.f; }

        o_c = o_n1; o_n1 = o_n2; o_n2 = o_n3;
        int tn = t0 + n + 4;
        o_n3 = ob[(tn <= TLEN - 1) ? tn : TLEN - 1];
    }
    sraw += __logf(lp);

    // store per-column sigma and the Q panel ([col][row] layout, f16)
    const int bc = b * nchunk + c;
    if (l < 16)
        Sig[bc * NSP + p * 16 + l] = (float)len * LN128 - sraw;
#pragma unroll
    for (int ic = 0; ic < 9; ++ic) {
        size_t off = ((size_t)bc * NSP + p * 16 + (l & 15)) * NSP + ic * 16 + g4;
        *(uint2*)(Qt + off) = __builtin_bit_cast(uint2, q[ic]);
    }
}

// ---------------------------------------------------------------------------
// Combine: chain alpha through the C chunk operators (f32, log-space).
// 32 blocks x 64 threads; lane holds states 2l, 2l+1 (+extras on lanes 0,1).
// ---------------------------------------------------------------------------
__global__ __launch_bounds__(64)
void hmm_combine_kernel(
    const half_t* __restrict__ Qt,
    const float* __restrict__ Sig,
    const float* __restrict__ Bm,      // original f32 [132][126]
    const float* __restrict__ I0,
    const unsigned short* __restrict__ obs,
    float* __restrict__ out,
    int nchunk)
{
    __shared__ float awL[NS + 4];
    const int l = threadIdx.x, b = blockIdx.x;
    const int j0 = 2 * l;

    int o0 = obs[(size_t)b * TLEN];
    float a0 = I0[j0]     * Bm[j0 * NA + o0];
    float a1 = I0[j0 + 1] * Bm[(j0 + 1) * NA + o0];
    float ax0 = 0.f, ax1 = 0.f;
    if (l < 2) {
        int jx = 128 + 2 * l;
        ax0 = I0[jx]     * Bm[jx * NA + o0];
        ax1 = I0[jx + 1] * Bm[(jx + 1) * NA + o0];
    }
    float S = wsum(a0 + a1 + ax0 + ax1);
    float ll = __logf(S);
    float inv = 1.f / S;
    float an0 = a0 * inv, an1 = a1 * inv, anx0 = ax0 * inv, anx1 = ax1 * inv;

    for (int c = 0; c < nchunk; ++c) {
        const float* sg = Sig + (size_t)(b * nchunk + c) * NSP;
        float s0 = sg[j0], s1 = sg[j0 + 1];
        float m = fminf(s0, s1);
        float sx0 = 0.f, sx1 = 0.f;
        if (l < 2) {
            sx0 = sg[128 + 2 * l]; sx1 = sg[129 + 2 * l];
            m = fminf(m, fminf(sx0, sx1));
        }
        float smin = wmin(m);

        awL[j0]     = an0 * __expf(smin - s0);
        awL[j0 + 1] = an1 * __expf(smin - s1);
        if (l < 2) {
            awL[128 + 2 * l] = anx0 * __expf(smin - sx0);
            awL[129 + 2 * l] = anx1 * __expf(smin - sx1);
        }
        __syncthreads();

        const half_t* Qc = Qt + (size_t)(b * nchunk + c) * NSP * NSP;
        float y0 = 0.f, y1 = 0.f, yx0 = 0.f, yx1 = 0.f;
        for (int i = 0; i < NS; ++i) {
            float av = awL[i];
            unsigned u = *(const unsigned*)(Qc + (size_t)i * NSP + j0);
            h2 h = bch2(u);
            y0 += av * (float)h.x;
            y1 += av * (float)h.y;
            if (l < 2) {
                unsigned ux = *(const unsigned*)(Qc + (size_t)i * NSP + 128 + 2 * l);
                h2 hx = bch2(ux);
                yx0 += av * (float)hx.x;
                yx1 += av * (float)hx.y;
            }
        }
        float Sc = wsum(y0 + y1 + yx0 + yx1);
        ll += __logf(Sc) - smin;
        float inv2 = 1.f / Sc;
        an0 = y0 * inv2; an1 = y1 * inv2; anx0 = yx0 * inv2; anx1 = yx1 * inv2;
        __syncthreads();
    }
    if (l == 0) out[b] = ll;
}

// ---------------------------------------------------------------------------
extern "C" void kernel_launch(void* const* d_in, const int* in_sizes, int n_in,
                              void* d_out, int out_size, void* d_ws, size_t ws_size,
                              hipStream_t stream) {
    const float* x  = (const float*)d_in[0];  // [32,10000,126] one-hot fp32
    const float* A  = (const float*)d_in[1];  // [132,132]
    const float* Bm = (const float*)d_in[2];  // [132,126]
    const float* I0 = (const float*)d_in[3];  // [132]
    float* out = (float*)d_out;               // [32] fp32

    char* ws = (char*)d_ws;
    unsigned short* obs = (unsigned short*)(ws + OBS_OFF);
    uint2*  Ah  = (uint2*)(ws + AT_OFF);
    half_t* emt = (half_t*)(ws + EM_OFF);

    // tier the chunk count by workspace size (round 10 proved >= 11.48 MB)
    auto need = [](int C) -> size_t {
        size_t qt = (size_t)SIG_OFF + (size_t)NBATCH * C * NSP * 4;
        qt = (qt + 63) & ~(size_t)63;
        return qt + (size_t)NBATCH * C * NSP * NSP * 2;
    };
    int C = 16;
    if (ws_size < need(16)) C = 8;
    size_t qt_off = ((size_t)SIG_OFF + (size_t)NBATCH * C * NSP * 4 + 63) & ~(size_t)63;
    float*  Sig = (float*)(ws + SIG_OFF);
    half_t* Qt  = (half_t*)(ws + qt_off);
    const int lenbase = (TLEN - 1 + C - 1) / C;   // 625 for C=16, 1250 for C=8

    const int total = NBATCH * TLEN;
    onehot_to_idx_kernel<<<(total + 3) / 4, 256, 0, stream>>>(x, obs, total);
    pack_At_kernel<<<(81 * 64 + 255) / 256, 256, 0, stream>>>(A, Ah);
    pack_em_kernel<<<(NA * EMS + 255) / 256, 256, 0, stream>>>(Bm, emt);

    hmm_chunk_kernel<<<NBATCH * C * 3, 192, 0, stream>>>(Ah, emt, obs, Qt, Sig, C, lenbase);
    hmm_combine_kernel<<<NBATCH, 64, 0, stream>>>(Qt, Sig, Bm, I0, obs, out, C);
}

// Round 12
// 2903.769 us; speedup vs baseline: 3.0587x; 1.0753x over previous
//
#include <hip/hip_runtime.h>

// ---------------------------------------------------------------------------
// Scaled HMM forward, B=32 rows, T=10000 serial steps, N=132 states.
// ROUND-12: chunked matrix-product scan (verified absmax 0.0 in r10/r11),
// restructured for OCCUPANCY. Round 11 ran at 1 wave/SIMD: 116 VGPR + 162
// AGPR (at_ fragments) = 278 combined > 256 (per-SIMD pool = 512) -> every
// dependency latency exposed (1824cy/step vs ~500cy issue).
// Changes:
//  * block = ONE wave, one panel. grid = 32 b x C chunks x 9 panels.
//  * NO LDS: em rows read from global (37KB table, L2-hot on all XCDs);
//    9x8B loads/step issued at loop top, consumed ~350cy later.
//  * __launch_bounds__(64, 2): min 2 waves/EU -> allocator budget 256 regs.
//    Estimated peak ~252 (at_162 + q18 + d36 + emc18 + misc).
// Math identical: Q_new = diag(em_o) (At @ Q) per 16-col panel via
// v_mfma_f32_16x16x16f16 (D rows == B k-slots per lane -> recurrence stays
// in registers); per-column 1-lag normalization g = 128*rcp(zp); exact log
// bookkeeping  sigma_col = len*ln128 - sum ln(z_col).
// ---------------------------------------------------------------------------

typedef _Float16 half_t;
typedef half_t h2 __attribute__((ext_vector_type(2)));
typedef half_t half4 __attribute__((ext_vector_type(4)));
typedef float  f32x4 __attribute__((ext_vector_type(4)));
typedef unsigned int uint2v __attribute__((ext_vector_type(2)));

#define FDOT2(a, b, acc) __builtin_amdgcn_fdot2((a), (b), (acc), false)

#define NS 132
#define NA 126
#define NSP 144        // padded states: 9 tiles of 16
#define EMS 148        // em row stride in halves (296 B)
#define TLEN 10000
#define NBATCH 32
#define LN128 4.852030263919617f

// ws layout (bytes)
#define OBS_OFF 0                    // 32*10000*2 = 640000 (+pad)
#define AT_OFF  640064               // 81*64*8 = 41472
#define EM_OFF  (AT_OFF + 81*64*8)   // 681536; 126*148*2 = 37296 -> ends 718832
#define SIG_OFF 718848               // 64-aligned

static __device__ __forceinline__ h2 bch2(unsigned int u) {
    return __builtin_bit_cast(h2, u);
}
static __device__ __forceinline__ unsigned int bcu(h2 v) {
    return __builtin_bit_cast(unsigned int, v);
}
static __device__ __forceinline__ h2 pkrtz(float a, float b) {
    return __builtin_bit_cast(h2, __builtin_amdgcn_cvt_pkrtz(a, b));
}
static __device__ __forceinline__ half4 mk4(h2 a, h2 b) {
    uint2 u = make_uint2(bcu(a), bcu(b));
    return __builtin_bit_cast(half4, u);
}
static __device__ __forceinline__ float xadd16(float v) {
#if __has_builtin(__builtin_amdgcn_permlane16_swap)
    uint2v r = __builtin_amdgcn_permlane16_swap(
        __builtin_bit_cast(unsigned int, v), __builtin_bit_cast(unsigned int, v),
        false, false);
    return __builtin_bit_cast(float, r[0]) + __builtin_bit_cast(float, r[1]);
#else
    return v + __shfl_xor(v, 16, 64);
#endif
}
static __device__ __forceinline__ float xadd32(float v) {
#if __has_builtin(__builtin_amdgcn_permlane32_swap)
    uint2v r = __builtin_amdgcn_permlane32_swap(
        __builtin_bit_cast(unsigned int, v), __builtin_bit_cast(unsigned int, v),
        false, false);
    return __builtin_bit_cast(float, r[0]) + __builtin_bit_cast(float, r[1]);
#else
    return v + __shfl_xor(v, 32, 64);
#endif
}
static __device__ __forceinline__ float wsum(float v) {
#pragma unroll
    for (int o = 32; o; o >>= 1) v += __shfl_xor(v, o, 64);
    return v;
}
static __device__ __forceinline__ float wmin(float v) {
#pragma unroll
    for (int o = 32; o; o >>= 1) v = fminf(v, __shfl_xor(v, o, 64));
    return v;
}

// ---------------------------------------------------------------------------
// one-hot [B*T, 126] fp32 -> index obs[b*T + t] (ushort). One wave per (b,t).
// ---------------------------------------------------------------------------
__global__ void onehot_to_idx_kernel(const float* __restrict__ x,
                                     unsigned short* __restrict__ obs, int total) {
    int wid  = (int)((blockIdx.x * blockDim.x + threadIdx.x) >> 6);
    int lane = threadIdx.x & 63;
    if (wid >= total) return;
    const float* row = x + (size_t)wid * NA;
    float v0 = row[lane];
    float v1 = (lane < NA - 64) ? row[64 + lane] : 0.0f;
    unsigned long long b0 = __ballot(v0 > 0.5f);
    unsigned long long b1 = __ballot(v1 > 0.5f);
    int idx = b0 ? (__ffsll(b0) - 1) : (64 + __ffsll(b1) - 1);
    if (lane == 0) obs[wid] = (unsigned short)idx;
}

// A-operand fragments: tile (jt, ic), lane l, elems e=0..3:
//   At[j][i] = A[i][j] with j = jt*16 + (l&15), i = ic*16 + (l>>4)*4 + e
__global__ void pack_At_kernel(const float* __restrict__ A, uint2* __restrict__ Ah) {
    int idx = blockIdx.x * 256 + threadIdx.x;
    if (idx >= 81 * 64) return;
    int tile = idx >> 6, l = idx & 63;
    int jt = tile / 9, ic = tile % 9;
    int j  = jt * 16 + (l & 15);
    int i0 = ic * 16 + ((l >> 4) << 2);
    float v[4];
#pragma unroll
    for (int e = 0; e < 4; ++e) {
        int i = i0 + e;
        v[e] = (i < NS && j < NS) ? A[i * NS + j] : 0.0f;
    }
    h2 p01 = {(half_t)v[0], (half_t)v[1]};
    h2 p23 = {(half_t)v[2], (half_t)v[3]};
    Ah[idx] = make_uint2(bcu(p01), bcu(p23));
}

// emt[o][j] = f16(B[j][o]) for j<132, else 0.  [126][EMS]
__global__ void pack_em_kernel(const float* __restrict__ B, half_t* __restrict__ emt) {
    int idx = blockIdx.x * 256 + threadIdx.x;
    if (idx >= NA * EMS) return;
    int o = idx / EMS, j = idx % EMS;
    emt[idx] = (j < NS) ? (half_t)B[j * NA + o] : (half_t)0.f;
}

// ---------------------------------------------------------------------------
// Chunk operators: grid = 32 b x C chunks x 9 panels, ONE WAVE per block.
// ---------------------------------------------------------------------------
__global__ __launch_bounds__(64, 2)
void hmm_chunk_kernel(
    const uint2* __restrict__ Ah,       // [81][64] A-frags
    const half_t* __restrict__ emt,     // [126][EMS] in global (L2-hot)
    const unsigned short* __restrict__ obs,  // [32][10000]
    half_t* __restrict__ Qt,            // [32*C][144 cols][144 rows] f16
    float* __restrict__ Sig,            // [32*C][144] per-column log-scale
    int nchunk, int lenbase)
{
    const int l   = threadIdx.x;
    const int blk = blockIdx.x;
    const int p   = blk % 9;                 // panel (16 cols of Q)
    const int c   = (blk / 9) % nchunk;      // chunk
    const int b   = blk / (9 * nchunk);      // batch row
    const int g4  = (l >> 4) << 2;           // row-group offset (0,4,8,12)

    // full At resident (162 regs; AGPR exile fine -- MFMA A-operand)
    half4 at_[9][9];
#pragma unroll
    for (int jt = 0; jt < 9; ++jt)
#pragma unroll
        for (int ic = 0; ic < 9; ++ic)
            at_[jt][ic] = __builtin_bit_cast(half4, Ah[(jt * 9 + ic) * 64 + l]);

    // Q = identity fragments for this panel
    half4 q[9];
    {
        const int colg = p * 16 + (l & 15);
#pragma unroll
        for (int ic = 0; ic < 9; ++ic) {
            const int k0 = ic * 16 + g4;
            h2 a01 = {(half_t)(k0     == colg ? 1.f : 0.f),
                      (half_t)(k0 + 1 == colg ? 1.f : 0.f)};
            h2 a23 = {(half_t)(k0 + 2 == colg ? 1.f : 0.f),
                      (half_t)(k0 + 3 == colg ? 1.f : 0.f)};
            q[ic] = mk4(a01, a23);
        }
    }

    const unsigned short* ob = obs + (size_t)b * TLEN;
    const half_t* emL = emt + g4;            // per-lane row base
    const int t0 = 1 + lenbase * c;
    int len = (TLEN - 1) - lenbase * c;
    if (len > lenbase) len = lenbase;

    // observation register pipeline (current + 3 ahead, clamped)
    int o_c  = ob[t0];
    int o_n1 = ob[(t0 + 1 <= TLEN - 1) ? t0 + 1 : TLEN - 1];
    int o_n2 = ob[(t0 + 2 <= TLEN - 1) ? t0 + 2 : TLEN - 1];
    int o_n3 = ob[(t0 + 3 <= TLEN - 1) ? t0 + 3 : TLEN - 1];

    float zp = 1.f, lp = 1.f, sraw = 0.f;
    const h2 ones = {(half_t)1.f, (half_t)1.f};
    const f32x4 Z4 = {0.f, 0.f, 0.f, 0.f};

#pragma clang loop unroll(disable)
    for (int n = 0; n < len; ++n) {
        // em reads for THIS step from global/L2 (~200cy), issued before the
        // MFMA block (~350cy of issue) -> latency covered
        uint2 emc[9];
        {
            const half_t* emrow = emL + o_c * EMS;
#pragma unroll
            for (int ic = 0; ic < 9; ++ic)
                emc[ic] = *(const uint2*)(emrow + ic * 16);
        }

        const float gsc = 128.f * __builtin_amdgcn_rcpf(zp);
        lp *= zp;                     // record the applied divisor
        const half_t gh = (half_t)gsc;
        const h2 g2 = {gh, gh};

        f32x4 d[9];
#pragma unroll
        for (int jt = 0; jt < 9; ++jt)
            d[jt] = __builtin_amdgcn_mfma_f32_16x16x16f16(
                        at_[jt][0], q[0], Z4, 0, 0, 0);
#pragma unroll
        for (int ic = 1; ic < 9; ++ic)
#pragma unroll
            for (int jt = 0; jt < 9; ++jt)
                d[jt] = __builtin_amdgcn_mfma_f32_16x16x16f16(
                            at_[jt][ic], q[ic], d[jt], 0, 0, 0);

        float za = 0.f, zb = 0.f, zc_ = 0.f, zd_ = 0.f;
#pragma unroll
        for (int jt = 0; jt < 9; ++jt) {
            h2 p01 = pkrtz(d[jt][0], d[jt][1]) * bch2(emc[jt].x) * g2;
            h2 p23 = pkrtz(d[jt][2], d[jt][3]) * bch2(emc[jt].y) * g2;
            q[jt] = mk4(p01, p23);
            if (jt & 1) { zc_ = FDOT2(p01, ones, zc_); zd_ = FDOT2(p23, ones, zd_); }
            else        { za  = FDOT2(p01, ones, za);  zb  = FDOT2(p23, ones, zb); }
        }
        float zs = (za + zb) + (zc_ + zd_);
        zs = xadd16(zs);              // 4 row-group lanes of this column
        zs = xadd32(zs);
        zp = fmaxf(zs, 1e-30f);       // dead-column guard (cols >= 132)

        if ((n & 3) == 3) { sraw += __logf(lp); lp = 1.f; }

        o_c = o_n1; o_n1 = o_n2; o_n2 = o_n3;
        int tn = t0 + n + 4;
        o_n3 = ob[(tn <= TLEN - 1) ? tn : TLEN - 1];
    }
    sraw += __logf(lp);

    // store per-column sigma and the Q panel ([col][row] layout, f16)
    const int bc = b * nchunk + c;
    if (l < 16)
        Sig[bc * NSP + p * 16 + l] = (float)len * LN128 - sraw;
#pragma unroll
    for (int ic = 0; ic < 9; ++ic) {
        size_t off = ((size_t)bc * NSP + p * 16 + (l & 15)) * NSP + ic * 16 + g4;
        *(uint2*)(Qt + off) = __builtin_bit_cast(uint2, q[ic]);
    }
}

// ---------------------------------------------------------------------------
// Combine: chain alpha through the C chunk operators (f32, log-space).
// 32 blocks x 64 threads; lane holds states 2l, 2l+1 (+extras on lanes 0,1).
// ---------------------------------------------------------------------------
__global__ __launch_bounds__(64)
void hmm_combine_kernel(
    const half_t* __restrict__ Qt,
    const float* __restrict__ Sig,
    const float* __restrict__ Bm,      // original f32 [132][126]
    const float* __restrict__ I0,
    const unsigned short* __restrict__ obs,
    float* __restrict__ out,
    int nchunk)
{
    __shared__ float awL[NS + 4];
    const int l = threadIdx.x, b = blockIdx.x;
    const int j0 = 2 * l;

    int o0 = obs[(size_t)b * TLEN];
    float a0 = I0[j0]     * Bm[j0 * NA + o0];
    float a1 = I0[j0 + 1] * Bm[(j0 + 1) * NA + o0];
    float ax0 = 0.f, ax1 = 0.f;
    if (l < 2) {
        int jx = 128 + 2 * l;
        ax0 = I0[jx]     * Bm[jx * NA + o0];
        ax1 = I0[jx + 1] * Bm[(jx + 1) * NA + o0];
    }
    float S = wsum(a0 + a1 + ax0 + ax1);
    float ll = __logf(S);
    float inv = 1.f / S;
    float an0 = a0 * inv, an1 = a1 * inv, anx0 = ax0 * inv, anx1 = ax1 * inv;

    for (int c = 0; c < nchunk; ++c) {
        const float* sg = Sig + (size_t)(b * nchunk + c) * NSP;
        float s0 = sg[j0], s1 = sg[j0 + 1];
        float m = fminf(s0, s1);
        float sx0 = 0.f, sx1 = 0.f;
        if (l < 2) {
            sx0 = sg[128 + 2 * l]; sx1 = sg[129 + 2 * l];
            m = fminf(m, fminf(sx0, sx1));
        }
        float smin = wmin(m);

        awL[j0]     = an0 * __expf(smin - s0);
        awL[j0 + 1] = an1 * __expf(smin - s1);
        if (l < 2) {
            awL[128 + 2 * l] = anx0 * __expf(smin - sx0);
            awL[129 + 2 * l] = anx1 * __expf(smin - sx1);
        }
        __syncthreads();

        const half_t* Qc = Qt + (size_t)(b * nchunk + c) * NSP * NSP;
        float y0 = 0.f, y1 = 0.f, yx0 = 0.f, yx1 = 0.f;
        for (int i = 0; i < NS; ++i) {
            float av = awL[i];
            unsigned u = *(const unsigned*)(Qc + (size_t)i * NSP + j0);
            h2 h = bch2(u);
            y0 += av * (float)h.x;
            y1 += av * (float)h.y;
            if (l < 2) {
                unsigned ux = *(const unsigned*)(Qc + (size_t)i * NSP + 128 + 2 * l);
                h2 hx = bch2(ux);
                yx0 += av * (float)hx.x;
                yx1 += av * (float)hx.y;
            }
        }
        float Sc = wsum(y0 + y1 + yx0 + yx1);
        ll += __logf(Sc) - smin;
        float inv2 = 1.f / Sc;
        an0 = y0 * inv2; an1 = y1 * inv2; anx0 = yx0 * inv2; anx1 = yx1 * inv2;
        __syncthreads();
    }
    if (l == 0) out[b] = ll;
}

// ---------------------------------------------------------------------------
extern "C" void kernel_launch(void* const* d_in, const int* in_sizes, int n_in,
                              void* d_out, int out_size, void* d_ws, size_t ws_size,
                              hipStream_t stream) {
    const float* x  = (const float*)d_in[0];  // [32,10000,126] one-hot fp32
    const float* A  = (const float*)d_in[1];  // [132,132]
    const float* Bm = (const float*)d_in[2];  // [132,126]
    const float* I0 = (const float*)d_in[3];  // [132]
    float* out = (float*)d_out;               // [32] fp32

    char* ws = (char*)d_ws;
    unsigned short* obs = (unsigned short*)(ws + OBS_OFF);
    uint2*  Ah  = (uint2*)(ws + AT_OFF);
    half_t* emt = (half_t*)(ws + EM_OFF);

    // tier the chunk count by workspace size (round 11 proved C=16 fits)
    auto need = [](int C) -> size_t {
        size_t qt = (size_t)SIG_OFF + (size_t)NBATCH * C * NSP * 4;
        qt = (qt + 63) & ~(size_t)63;
        return qt + (size_t)NBATCH * C * NSP * NSP * 2;
    };
    int C = 16;
    if (ws_size < need(16)) C = 8;
    size_t qt_off = ((size_t)SIG_OFF + (size_t)NBATCH * C * NSP * 4 + 63) & ~(size_t)63;
    float*  Sig = (float*)(ws + SIG_OFF);
    half_t* Qt  = (half_t*)(ws + qt_off);
    const int lenbase = (TLEN - 1 + C - 1) / C;   // 625 for C=16

    const int total = NBATCH * TLEN;
    onehot_to_idx_kernel<<<(total + 3) / 4, 256, 0, stream>>>(x, obs, total);
    pack_At_kernel<<<(81 * 64 + 255) / 256, 256, 0, stream>>>(A, Ah);
    pack_em_kernel<<<(NA * EMS + 255) / 256, 256, 0, stream>>>(Bm, emt);

    hmm_chunk_kernel<<<NBATCH * C * 9, 64, 0, stream>>>(Ah, emt, obs, Qt, Sig, C, lenbase);
    hmm_combine_kernel<<<NBATCH, 64, 0, stream>>>(Qt, Sig, Bm, I0, obs, out, C);
}